// Round 7
// baseline (38.836 us; speedup 1.0000x reference)
//
#include <hip/hip_runtime.h>

#define HID 128
#define FEAT 16
#define N_PER 100000
#define NUM_ACTIONS 75000
#define N_NODES 100000
#define N_GRAPHS 512

// ws float layout:
// [128..143] wg feat part   [272..287] wn feat part   [544..559] we feat part
// [688] cg=glob_b.p [689] cn=node_b.p [690] ce=e1_b.qEE+e2_b.p [691] pb
// [NSCAL_OFF + 4h]  nscal(h): (x=nodes.wr, y=nodes.wc, z=nodes.wn)
// [GSCAL_OFF + u]   gscal(u) = globs[u].wg
// [ESCAL_OFF + g]   escal(g) = edges[E[g]].qe
#define NSCAL_OFF 1024
#define GSCAL_OFF (NSCAL_OFF + 4 * N_NODES)
#define ESCAL_OFF (GSCAL_OFF + N_GRAPHS)

#define NODE_BLOCKS 116
#define EDGE_BLOCKS 140
#define PREP_BLOCKS (NODE_BLOCKS + EDGE_BLOCKS)

__device__ __forceinline__ float dot4(float4 a, float4 b) {
    return a.x * b.x + a.y * b.y + a.z * b.z + a.w * b.w;
}

// ---- DPP sum reductions (VALU-only, no LDS pipe) ----
template <int CTRL>
__device__ __forceinline__ float dpp_mov(float x) {
    return __int_as_float(__builtin_amdgcn_update_dpp(
        0, __float_as_int(x), CTRL, 0xF, 0xF, true));
}
// sum over 16-lane row; valid in lane 15 (mod 16)
__device__ __forceinline__ float red16(float x) {
    x += dpp_mov<0x111>(x);   // row_shr:1
    x += dpp_mov<0x112>(x);   // row_shr:2
    x += dpp_mov<0x114>(x);   // row_shr:4
    x += dpp_mov<0x118>(x);   // row_shr:8
    return x;
}
// sum over 32-lane half; valid in lane 31 (mod 32)
__device__ __forceinline__ float red32(float x) {
    x = red16(x);
    x += dpp_mov<0x142>(x);   // row_bcast:15
    return x;
}

// 256 blocks x 1024 threads, role-split.
// node-role (bid < 116): LDS-fold qEE -> wn,wr,wc; stream nodes -> nscal.
// edge-role: LDS-fold qe (+wg for first 16); gather edges[E[g]] -> escal;
//            first 16 edge blocks also write gscal.
__global__ __launch_bounds__(1024) void prep_kernel(
    const float* __restrict__ nodes, const float* __restrict__ globs,
    const float* __restrict__ edges,
    const float* __restrict__ glob_W, const float* __restrict__ glob_b,
    const float* __restrict__ node_W, const float* __restrict__ node_b,
    const float* __restrict__ e1_W,  const float* __restrict__ e1_b,
    const float* __restrict__ e2_W,  const float* __restrict__ e2_b,
    const float* __restrict__ pol_W, const float* __restrict__ pol_b,
    const int* __restrict__ E, float* __restrict__ ws)
{
    __shared__ float qEE[HID];
    __shared__ float wA[HID];
    __shared__ float wB[HID];
    __shared__ float wC[HID];
    const int t = threadIdx.x, hw = t >> 5, s = t & 31;
    const int bid = blockIdx.x;
    const float4 p4 = *(const float4*)&pol_W[4 * s];

    if (bid < NODE_BLOCKS) {
        // ---- fold: qEE = e2_W rows 128..255 @ p ----
        #pragma unroll
        for (int r = 0; r < 4; ++r) {
            const int k = hw + 32 * r;
            const float4 x = *(const float4*)&e2_W[(HID + k) * HID + 4 * s];
            const float acc = red32(dot4(x, p4));
            if (s == 31) qEE[k] = acc;
        }
        __syncthreads();
        const float4 q4 = *(const float4*)&qEE[4 * s];
        // ---- fold: wn, wr, wc ----
        for (int r = 0; r < 4; ++r) {
            const int k = hw + 32 * r;
            const float4 xn = *(const float4*)&node_W[k * HID + 4 * s];
            const float an_ = red32(dot4(xn, p4));
            if (s == 31) wA[k] = an_;
            const float4 xr = *(const float4*)&e1_W[k * HID + 4 * s];
            const float ar = red32(dot4(xr, q4));
            if (s == 31) wB[k] = ar;
            const float4 xc = *(const float4*)&e1_W[(144 + k) * HID + 4 * s];
            const float ac = red32(dot4(xc, q4));
            if (s == 31) wC[k] = ac;
        }
        if (bid == 0) {
            // feat parts + constants for the actions kernel
            {
                const int d = hw;  // 0..31
                const float* rp = (d < 16) ? &glob_W[(HID + d) * HID]
                                           : &node_W[(HID + (d - 16)) * HID];
                const float4 x = *(const float4*)&rp[4 * s];
                const float acc = red32(dot4(x, p4));
                if (s == 31) ws[d < 16 ? 128 + d : 272 + (d - 16)] = acc;
            }
            if (hw < 20) {
                float acc; int dst;
                if (hw < 16) {
                    const float4 x = *(const float4*)&e1_W[(HID + hw) * HID + 4 * s];
                    acc = dot4(x, q4); dst = 544 + hw;
                } else if (hw == 16) {
                    const float4 x = *(const float4*)&glob_b[4 * s];
                    acc = dot4(x, p4); dst = 688;
                } else if (hw == 17) {
                    const float4 x = *(const float4*)&node_b[4 * s];
                    acc = dot4(x, p4); dst = 689;
                } else if (hw == 18) {
                    const float4 x1 = *(const float4*)&e1_b[4 * s];
                    const float4 x2 = *(const float4*)&e2_b[4 * s];
                    acc = dot4(x1, q4) + dot4(x2, p4); dst = 690;
                } else {
                    acc = 0.f; dst = 691;
                }
                acc = red32(acc);
                if (s == 31) ws[dst] = (dst == 691) ? pol_b[0] : acc;
            }
        }
        __syncthreads();
        const float4 fn = *(const float4*)&wA[4 * s];
        const float4 fr = *(const float4*)&wB[4 * s];
        const float4 fc = *(const float4*)&wC[4 * s];
        for (int h = bid * 32 + hw; h < N_NODES; h += NODE_BLOCKS * 32) {
            const float4 x = *(const float4*)&nodes[h * HID + 4 * s];
            const float ar = red32(dot4(x, fr));
            const float ac = red32(dot4(x, fc));
            const float az = red32(dot4(x, fn));
            if (s == 31)
                *(float4*)&ws[NSCAL_OFF + 4 * h] = make_float4(ar, ac, az, 0.f);
        }
    } else {
        const int eb = bid - NODE_BLOCKS;   // 0..EDGE_BLOCKS-1
        // ---- fold: qe = e2_W rows 0..127 @ p ----
        #pragma unroll
        for (int r = 0; r < 4; ++r) {
            const int k = hw + 32 * r;
            const float4 x = *(const float4*)&e2_W[k * HID + 4 * s];
            const float acc = red32(dot4(x, p4));
            if (s == 31) wA[k] = acc;
        }
        if (eb < 16) {
            // wg = glob_W rows 0..127 @ p (for gscal)
            #pragma unroll
            for (int r = 0; r < 4; ++r) {
                const int k = hw + 32 * r;
                const float4 x = *(const float4*)&glob_W[k * HID + 4 * s];
                const float acc = red32(dot4(x, p4));
                if (s == 31) wB[k] = acc;
            }
        }
        __syncthreads();
        const float4 q4 = *(const float4*)&wA[4 * s];
        if (eb < 16) {
            const float4 g4 = *(const float4*)&wB[4 * s];
            const int u = eb * 32 + hw;            // 16*32 = 512 graphs
            const float4 x = *(const float4*)&globs[u * HID + 4 * s];
            const float a = red32(dot4(x, g4));
            if (s == 31) ws[GSCAL_OFF + u] = a;
        }
        // ---- edges gather with E prefetch ----
        int g = eb * 32 + hw;
        const int stride = EDGE_BLOCKS * 32;
        int e = (g < N_PER) ? E[g] : 0;
        while (g < N_PER) {
            const int gn = g + stride;
            const int en = (gn < N_PER) ? E[gn] : 0;
            const float4 x = *(const float4*)&edges[e * HID + 4 * s];
            const float acc = red32(dot4(x, q4));
            if (s == 31) ws[ESCAL_OFF + g] = acc;
            g = gn; e = en;
        }
    }
}

// One 16-lane quarter-wave per action: feat dot over the action's 4 rows
// (256B coalesced) + scalar table lookups, red16, one store.
__global__ __launch_bounds__(256) void actions_kernel(
    const float* __restrict__ ag, const float* __restrict__ an,
    const float* __restrict__ ae,
    const int* __restrict__ row, const int* __restrict__ col,
    const int* __restrict__ U, const int* __restrict__ V,
    const int* __restrict__ E,
    const float* __restrict__ ws, float* __restrict__ out)
{
    const int tid = threadIdx.x;
    const int qg  = tid >> 4;            // quarter id in block 0..15
    const int ql  = tid & 15;
    const int a   = blockIdx.x * 16 + qg;
    if (a >= NUM_ACTIONS) return;

    float p;
    if (a < 25000) {
        const int gl = 4 * a;
        const float4 f  = *(const float4*)&ag[gl * FEAT + 4 * ql];
        const float4 wf = *(const float4*)&ws[128 + 4 * (ql & 3)];
        p = dot4(f, wf);
        if ((ql & 3) == 0) p += ws[GSCAL_OFF + U[gl + (ql >> 2)]];
        p = red16(p);
        if (ql == 15) out[a] = p + 4.f * ws[688] + ws[691];
    } else if (a < 50000) {
        const int gl = 4 * (a - 25000);
        const float4 f  = *(const float4*)&an[gl * FEAT + 4 * ql];
        const float4 wf = *(const float4*)&ws[272 + 4 * (ql & 3)];
        p = dot4(f, wf);
        if ((ql & 3) == 0) p += ws[NSCAL_OFF + 4 * V[gl + (ql >> 2)] + 2];
        p = red16(p);
        if (ql == 15) out[a] = p + 4.f * ws[689] + ws[691];
    } else {
        const int gl = 4 * (a - 50000);
        const float4 f  = *(const float4*)&ae[gl * FEAT + 4 * ql];
        const float4 wf = *(const float4*)&ws[544 + 4 * (ql & 3)];
        p = dot4(f, wf);
        if (ql < 8) {
            const int e  = E[gl + (ql & 3)];
            const int id = (ql < 4) ? row[e] : col[e];
            p += ws[NSCAL_OFF + 4 * id + ((ql < 4) ? 0 : 1)];
        } else if (ql < 12) {
            p += ws[ESCAL_OFF + gl + (ql - 8)];
        }
        p = red16(p);
        if (ql == 15) out[a] = p + 4.f * ws[690] + ws[691];
    }
}

extern "C" void kernel_launch(void* const* d_in, const int* in_sizes, int n_in,
                              void* d_out, int out_size, void* d_ws, size_t ws_size,
                              hipStream_t stream)
{
    const float* globs  = (const float*)d_in[0];
    const float* nodes  = (const float*)d_in[1];
    const float* edges  = (const float*)d_in[2];
    const float* ag     = (const float*)d_in[3];
    const float* an     = (const float*)d_in[4];
    const float* ae     = (const float*)d_in[5];
    const float* glob_W = (const float*)d_in[6];
    const float* glob_b = (const float*)d_in[7];
    const float* node_W = (const float*)d_in[8];
    const float* node_b = (const float*)d_in[9];
    const float* e1_W   = (const float*)d_in[10];
    const float* e1_b   = (const float*)d_in[11];
    const float* e2_W   = (const float*)d_in[12];
    const float* e2_b   = (const float*)d_in[13];
    const float* pol_W  = (const float*)d_in[14];
    const float* pol_b  = (const float*)d_in[15];
    const int*   row    = (const int*)d_in[16];
    const int*   col    = (const int*)d_in[17];
    const int*   U      = (const int*)d_in[18];
    const int*   V      = (const int*)d_in[20];
    const int*   E      = (const int*)d_in[22];

    float* ws  = (float*)d_ws;
    float* out = (float*)d_out;

    hipLaunchKernelGGL(prep_kernel, dim3(PREP_BLOCKS), dim3(1024), 0, stream,
                       nodes, globs, edges, glob_W, glob_b, node_W, node_b,
                       e1_W, e1_b, e2_W, e2_b, pol_W, pol_b, E, ws);
    hipLaunchKernelGGL(actions_kernel, dim3((NUM_ACTIONS + 15) / 16), dim3(256),
                       0, stream, ag, an, ae, row, col, U, V, E, ws, out);
}

// Round 8
// 36.118 us; speedup vs baseline: 1.0752x; 1.0752x over previous
//
#include <hip/hip_runtime.h>

#define HID 128
#define FEAT 16
#define N_PER 100000
#define NUM_ACTIONS 75000
#define N_NODES 100000
#define N_GRAPHS 512

// ws float layout:
// [0..143]   wg   (globs part 0..127, feat part 128..143)
// [144..287] wn   (nodes part 144..271, feat part 272..287)
// [288..415] qe
// [416..687] w1   (row 416..543, feat 544..559, col 560..687)
// [688] cg [689] cn [690] ce [691] pb
// [NSCAL_OFF + 4h]  nscal(h): (x=nodes.wr, y=nodes.wc, z=nodes.wn)
// [GSCAL_OFF + u]   gscal(u) = globs[u].wg
// [ESCAL_OFF + g]   escal(g) = edges[E[g]].qe
#define NSCAL_OFF 1024
#define GSCAL_OFF (NSCAL_OFF + 4 * N_NODES)
#define ESCAL_OFF (GSCAL_OFF + N_GRAPHS)

#define NB 896
#define EB 1120
#define GB 16
#define WORK_BLOCKS (NB + EB + GB)

__device__ __forceinline__ float dot4(float4 a, float4 b) {
    return a.x * b.x + a.y * b.y + a.z * b.z + a.w * b.w;
}

// ---- DPP sum reductions (VALU-only, no LDS pipe) ----
template <int CTRL>
__device__ __forceinline__ float dpp_mov(float x) {
    return __int_as_float(__builtin_amdgcn_update_dpp(
        0, __float_as_int(x), CTRL, 0xF, 0xF, true));
}
__device__ __forceinline__ float red16(float x) {
    x += dpp_mov<0x111>(x);   // row_shr:1
    x += dpp_mov<0x112>(x);   // row_shr:2
    x += dpp_mov<0x114>(x);   // row_shr:4
    x += dpp_mov<0x118>(x);   // row_shr:8
    return x;                 // valid in lane 15 (mod 16)
}
__device__ __forceinline__ float red32(float x) {
    x = red16(x);
    x += dpp_mov<0x142>(x);   // row_bcast:15
    return x;                 // valid in lane 31 (mod 32)
}
__device__ __forceinline__ float red64(float x) {
    x = red32(x);
    x += dpp_mov<0x143>(x);   // row_bcast:31
    return x;                 // valid in lane 63
}

// 44 blocks x 1024 threads (R6 version, proven). Blocks 26..43 build qEE in
// LDS; each wave then does <=1 of the 692 folded dots.
__global__ __launch_bounds__(1024) void fold_kernel(
    const float* __restrict__ glob_W, const float* __restrict__ glob_b,
    const float* __restrict__ node_W, const float* __restrict__ node_b,
    const float* __restrict__ e1_W,  const float* __restrict__ e1_b,
    const float* __restrict__ e2_W,  const float* __restrict__ e2_b,
    const float* __restrict__ pol_W, const float* __restrict__ pol_b,
    float* __restrict__ ws)
{
    __shared__ float qEE[HID];
    const int t = threadIdx.x, wave = t >> 6, lane = t & 63;
    const int bid = blockIdx.x;

    const bool needq = (bid >= 26 && bid <= 43);
    if (needq) {
        const int hw = t >> 5, s = t & 31;
        const float4 p4 = *(const float4*)&pol_W[4 * s];
        #pragma unroll
        for (int r = 0; r < 4; ++r) {
            const int k = hw + 32 * r;
            const float4 x = *(const float4*)&e2_W[(HID + k) * HID + 4 * s];
            float acc = red32(dot4(x, p4));
            if (s == 31) qEE[k] = acc;
        }
        __syncthreads();
    }

    const float2 p2 = *(const float2*)&pol_W[2 * lane];
    const int d = bid * 16 + wave;
    if (d == 691) {
        if (lane == 0) ws[691] = pol_b[0];
    } else if (d < 692) {
        float acc;
        if (d < 144) {
            const float2 x = *(const float2*)&glob_W[d * HID + 2 * lane];
            acc = x.x * p2.x + x.y * p2.y;
        } else if (d < 288) {
            const float2 x = *(const float2*)&node_W[(d - 144) * HID + 2 * lane];
            acc = x.x * p2.x + x.y * p2.y;
        } else if (d < 416) {
            const float2 x = *(const float2*)&e2_W[(d - 288) * HID + 2 * lane];
            acc = x.x * p2.x + x.y * p2.y;
        } else if (d < 688) {
            const float2 q2 = *(const float2*)&qEE[2 * lane];
            const float2 x  = *(const float2*)&e1_W[(d - 416) * HID + 2 * lane];
            acc = x.x * q2.x + x.y * q2.y;
        } else if (d == 688) {
            const float2 x = *(const float2*)&glob_b[2 * lane];
            acc = x.x * p2.x + x.y * p2.y;
        } else if (d == 689) {
            const float2 x = *(const float2*)&node_b[2 * lane];
            acc = x.x * p2.x + x.y * p2.y;
        } else { // 690
            const float2 q2 = *(const float2*)&qEE[2 * lane];
            const float2 x1 = *(const float2*)&e1_b[2 * lane];
            const float2 x2 = *(const float2*)&e2_b[2 * lane];
            acc = x1.x * q2.x + x1.y * q2.y + x2.x * p2.x + x2.y * p2.y;
        }
        acc = red64(acc);
        if (lane == 63) ws[d] = acc;
    }
}

// 2032 blocks x 256 threads, role-split by bid; roles co-resident per CU.
// node role: stream nodes -> nscal. edge role: gather edges[E[g]] -> escal
// (E prefetched). gscal role: 16 blocks for the 512 graphs.
__global__ __launch_bounds__(256) void work_kernel(
    const float* __restrict__ nodes, const float* __restrict__ globs,
    const float* __restrict__ edges, const int* __restrict__ E,
    float* __restrict__ ws)
{
    const int t = threadIdx.x, hw = t >> 5, s = t & 31;  // 8 half-waves/block
    const int bid = blockIdx.x;

    if (bid < NB) {
        const float4 fr = *(const float4*)&ws[416 + 4 * s];
        const float4 fc = *(const float4*)&ws[560 + 4 * s];
        const float4 fn = *(const float4*)&ws[144 + 4 * s];
        for (int h = bid * 8 + hw; h < N_NODES; h += NB * 8) {
            const float4 x = *(const float4*)&nodes[h * HID + 4 * s];
            const float ar = red32(dot4(x, fr));
            const float ac = red32(dot4(x, fc));
            const float az = red32(dot4(x, fn));
            if (s == 31)
                *(float4*)&ws[NSCAL_OFF + 4 * h] = make_float4(ar, ac, az, 0.f);
        }
    } else if (bid < NB + EB) {
        const int eb = bid - NB;
        const float4 q4 = *(const float4*)&ws[288 + 4 * s];
        int g = eb * 8 + hw;
        const int stride = EB * 8;
        int e = (g < N_PER) ? E[g] : 0;
        while (g < N_PER) {
            const int gn = g + stride;
            const int en = (gn < N_PER) ? E[gn] : 0;
            const float4 x = *(const float4*)&edges[e * HID + 4 * s];
            const float acc = red32(dot4(x, q4));
            if (s == 31) ws[ESCAL_OFF + g] = acc;
            g = gn; e = en;
        }
    } else {
        const int gb = bid - NB - EB;  // 0..15
        const float4 g4 = *(const float4*)&ws[4 * s];
        for (int u = gb * 8 + hw; u < N_GRAPHS; u += GB * 8) {
            const float4 x = *(const float4*)&globs[u * HID + 4 * s];
            const float a = red32(dot4(x, g4));
            if (s == 31) ws[GSCAL_OFF + u] = a;
        }
    }
}

// One 16-lane quarter-wave per action: feat dot over the action's 4 rows
// (256B coalesced) + scalar table lookups, red16, one store.
__global__ __launch_bounds__(256) void actions_kernel(
    const float* __restrict__ ag, const float* __restrict__ an,
    const float* __restrict__ ae,
    const int* __restrict__ row, const int* __restrict__ col,
    const int* __restrict__ U, const int* __restrict__ V,
    const int* __restrict__ E,
    const float* __restrict__ ws, float* __restrict__ out)
{
    const int tid = threadIdx.x;
    const int qg  = tid >> 4;            // quarter id in block 0..15
    const int ql  = tid & 15;
    const int a   = blockIdx.x * 16 + qg;
    if (a >= NUM_ACTIONS) return;

    float p;
    if (a < 25000) {
        const int gl = 4 * a;
        const float4 f  = *(const float4*)&ag[gl * FEAT + 4 * ql];
        const float4 wf = *(const float4*)&ws[128 + 4 * (ql & 3)];
        p = dot4(f, wf);
        if ((ql & 3) == 0) p += ws[GSCAL_OFF + U[gl + (ql >> 2)]];
        p = red16(p);
        if (ql == 15) out[a] = p + 4.f * ws[688] + ws[691];
    } else if (a < 50000) {
        const int gl = 4 * (a - 25000);
        const float4 f  = *(const float4*)&an[gl * FEAT + 4 * ql];
        const float4 wf = *(const float4*)&ws[272 + 4 * (ql & 3)];
        p = dot4(f, wf);
        if ((ql & 3) == 0) p += ws[NSCAL_OFF + 4 * V[gl + (ql >> 2)] + 2];
        p = red16(p);
        if (ql == 15) out[a] = p + 4.f * ws[689] + ws[691];
    } else {
        const int gl = 4 * (a - 50000);
        const float4 f  = *(const float4*)&ae[gl * FEAT + 4 * ql];
        const float4 wf = *(const float4*)&ws[544 + 4 * (ql & 3)];
        p = dot4(f, wf);
        if (ql < 8) {
            const int e  = E[gl + (ql & 3)];
            const int id = (ql < 4) ? row[e] : col[e];
            p += ws[NSCAL_OFF + 4 * id + ((ql < 4) ? 0 : 1)];
        } else if (ql < 12) {
            p += ws[ESCAL_OFF + gl + (ql - 8)];
        }
        p = red16(p);
        if (ql == 15) out[a] = p + 4.f * ws[690] + ws[691];
    }
}

extern "C" void kernel_launch(void* const* d_in, const int* in_sizes, int n_in,
                              void* d_out, int out_size, void* d_ws, size_t ws_size,
                              hipStream_t stream)
{
    const float* globs  = (const float*)d_in[0];
    const float* nodes  = (const float*)d_in[1];
    const float* edges  = (const float*)d_in[2];
    const float* ag     = (const float*)d_in[3];
    const float* an     = (const float*)d_in[4];
    const float* ae     = (const float*)d_in[5];
    const float* glob_W = (const float*)d_in[6];
    const float* glob_b = (const float*)d_in[7];
    const float* node_W = (const float*)d_in[8];
    const float* node_b = (const float*)d_in[9];
    const float* e1_W   = (const float*)d_in[10];
    const float* e1_b   = (const float*)d_in[11];
    const float* e2_W   = (const float*)d_in[12];
    const float* e2_b   = (const float*)d_in[13];
    const float* pol_W  = (const float*)d_in[14];
    const float* pol_b  = (const float*)d_in[15];
    const int*   row    = (const int*)d_in[16];
    const int*   col    = (const int*)d_in[17];
    const int*   U      = (const int*)d_in[18];
    const int*   V      = (const int*)d_in[20];
    const int*   E      = (const int*)d_in[22];

    float* ws  = (float*)d_ws;
    float* out = (float*)d_out;

    hipLaunchKernelGGL(fold_kernel, dim3(44), dim3(1024), 0, stream,
                       glob_W, glob_b, node_W, node_b, e1_W, e1_b, e2_W, e2_b,
                       pol_W, pol_b, ws);
    hipLaunchKernelGGL(work_kernel, dim3(WORK_BLOCKS), dim3(256), 0, stream,
                       nodes, globs, edges, E, ws);
    hipLaunchKernelGGL(actions_kernel, dim3((NUM_ACTIONS + 15) / 16), dim3(256),
                       0, stream, ag, an, ae, row, col, U, V, E, ws, out);
}

// Round 9
// 35.715 us; speedup vs baseline: 1.0874x; 1.0113x over previous
//
#include <hip/hip_runtime.h>

#define HID 128
#define FEAT 16
#define N_PER 100000
#define NUM_ACTIONS 75000
#define N_NODES 100000
#define N_GRAPHS 512

// ws float layout:
// [0..143]   wg   (globs part 0..127, feat part 128..143)
// [144..287] wn   (nodes part 144..271, feat part 272..287)
// [288..415] qe
// [416..687] w1   (row 416..543, feat 544..559, col 560..687)
// [688] cg [689] cn [690] ce [691] pb
// [NSCAL_OFF + 4h]  nscal(h): (x=nodes.wr, y=nodes.wc, z=nodes.wn)
// [GSCAL_OFF + u]   gscal(u) = globs[u].wg
// [ESCAL_OFF + g]   escal(g) = edges[E[g]].qe
// [PSUM_OFF + a]    psum(a)  = per-action feat-dot partial
#define NSCAL_OFF 1024
#define GSCAL_OFF (NSCAL_OFF + 4 * N_NODES)
#define ESCAL_OFF (GSCAL_OFF + N_GRAPHS)
#define PSUM_OFF  (ESCAL_OFF + N_PER)

#define NB 760
#define EB 968
#define FB 288
#define GB 16
#define WORK_BLOCKS (NB + EB + FB + GB)

__device__ __forceinline__ float dot4(float4 a, float4 b) {
    return a.x * b.x + a.y * b.y + a.z * b.z + a.w * b.w;
}

// ---- DPP sum reductions (VALU-only, no LDS pipe) ----
template <int CTRL>
__device__ __forceinline__ float dpp_mov(float x) {
    return __int_as_float(__builtin_amdgcn_update_dpp(
        0, __float_as_int(x), CTRL, 0xF, 0xF, true));
}
__device__ __forceinline__ float red16(float x) {
    x += dpp_mov<0x111>(x);   // row_shr:1
    x += dpp_mov<0x112>(x);   // row_shr:2
    x += dpp_mov<0x114>(x);   // row_shr:4
    x += dpp_mov<0x118>(x);   // row_shr:8
    return x;                 // valid in lane 15 (mod 16)
}
__device__ __forceinline__ float red32(float x) {
    x = red16(x);
    x += dpp_mov<0x142>(x);   // row_bcast:15
    return x;                 // valid in lane 31 (mod 32)
}
__device__ __forceinline__ float red64(float x) {
    x = red32(x);
    x += dpp_mov<0x143>(x);   // row_bcast:31
    return x;                 // valid in lane 63
}

// 44 blocks x 1024 threads (R6 version, proven). Blocks 26..43 build qEE in
// LDS; each wave then does <=1 of the 692 folded dots.
__global__ __launch_bounds__(1024) void fold_kernel(
    const float* __restrict__ glob_W, const float* __restrict__ glob_b,
    const float* __restrict__ node_W, const float* __restrict__ node_b,
    const float* __restrict__ e1_W,  const float* __restrict__ e1_b,
    const float* __restrict__ e2_W,  const float* __restrict__ e2_b,
    const float* __restrict__ pol_W, const float* __restrict__ pol_b,
    float* __restrict__ ws)
{
    __shared__ float qEE[HID];
    const int t = threadIdx.x, wave = t >> 6, lane = t & 63;
    const int bid = blockIdx.x;

    const bool needq = (bid >= 26 && bid <= 43);
    if (needq) {
        const int hw = t >> 5, s = t & 31;
        const float4 p4 = *(const float4*)&pol_W[4 * s];
        #pragma unroll
        for (int r = 0; r < 4; ++r) {
            const int k = hw + 32 * r;
            const float4 x = *(const float4*)&e2_W[(HID + k) * HID + 4 * s];
            float acc = red32(dot4(x, p4));
            if (s == 31) qEE[k] = acc;
        }
        __syncthreads();
    }

    const float2 p2 = *(const float2*)&pol_W[2 * lane];
    const int d = bid * 16 + wave;
    if (d == 691) {
        if (lane == 0) ws[691] = pol_b[0];
    } else if (d < 692) {
        float acc;
        if (d < 144) {
            const float2 x = *(const float2*)&glob_W[d * HID + 2 * lane];
            acc = x.x * p2.x + x.y * p2.y;
        } else if (d < 288) {
            const float2 x = *(const float2*)&node_W[(d - 144) * HID + 2 * lane];
            acc = x.x * p2.x + x.y * p2.y;
        } else if (d < 416) {
            const float2 x = *(const float2*)&e2_W[(d - 288) * HID + 2 * lane];
            acc = x.x * p2.x + x.y * p2.y;
        } else if (d < 688) {
            const float2 q2 = *(const float2*)&qEE[2 * lane];
            const float2 x  = *(const float2*)&e1_W[(d - 416) * HID + 2 * lane];
            acc = x.x * q2.x + x.y * q2.y;
        } else if (d == 688) {
            const float2 x = *(const float2*)&glob_b[2 * lane];
            acc = x.x * p2.x + x.y * p2.y;
        } else if (d == 689) {
            const float2 x = *(const float2*)&node_b[2 * lane];
            acc = x.x * p2.x + x.y * p2.y;
        } else { // 690
            const float2 q2 = *(const float2*)&qEE[2 * lane];
            const float2 x1 = *(const float2*)&e1_b[2 * lane];
            const float2 x2 = *(const float2*)&e2_b[2 * lane];
            acc = x1.x * q2.x + x1.y * q2.y + x2.x * p2.x + x2.y * p2.y;
        }
        acc = red64(acc);
        if (lane == 63) ws[d] = acc;
    }
}

// 2032 blocks x 256 threads, 4 roles by bid; all blocks co-resident.
// node: stream nodes -> nscal.  edge: gather edges[E[g]] -> escal.
// feat: stream ag/an/ae -> per-action psum.  gscal: 512 graphs.
__global__ __launch_bounds__(256) void work_kernel(
    const float* __restrict__ nodes, const float* __restrict__ globs,
    const float* __restrict__ edges,
    const float* __restrict__ ag, const float* __restrict__ an,
    const float* __restrict__ ae,
    const int* __restrict__ E, float* __restrict__ ws)
{
    const int t = threadIdx.x, hw = t >> 5, s = t & 31;  // 8 half-waves/block
    const int bid = blockIdx.x;

    if (bid < NB) {
        const float4 fr = *(const float4*)&ws[416 + 4 * s];
        const float4 fc = *(const float4*)&ws[560 + 4 * s];
        const float4 fn = *(const float4*)&ws[144 + 4 * s];
        for (int h = bid * 8 + hw; h < N_NODES; h += NB * 8) {
            const float4 x = *(const float4*)&nodes[h * HID + 4 * s];
            const float ar = red32(dot4(x, fr));
            const float ac = red32(dot4(x, fc));
            const float az = red32(dot4(x, fn));
            if (s == 31)
                *(float4*)&ws[NSCAL_OFF + 4 * h] = make_float4(ar, ac, az, 0.f);
        }
    } else if (bid < NB + EB) {
        const int eb = bid - NB;
        const float4 q4 = *(const float4*)&ws[288 + 4 * s];
        int g = eb * 8 + hw;
        const int stride = EB * 8;
        int e = (g < N_PER) ? E[g] : 0;
        while (g < N_PER) {
            const int gn = g + stride;
            const int en = (gn < N_PER) ? E[gn] : 0;
            const float4 x = *(const float4*)&edges[e * HID + 4 * s];
            const float acc = red32(dot4(x, q4));
            if (s == 31) ws[ESCAL_OFF + g] = acc;
            g = gn; e = en;
        }
    } else if (bid < NB + EB + FB) {
        const int fb = bid - NB - EB;
        const int qg = t >> 4, ql = t & 15;           // 16 actions/block/iter
        for (int a = fb * 16 + qg; a < NUM_ACTIONS; a += FB * 16) {
            const int br = a / 25000;
            const int gl = 4 * (a - br * 25000);
            const float* f = (br == 0) ? ag : (br == 1) ? an : ae;
            const int fbase = (br == 0) ? 128 : (br == 1) ? 272 : 544;
            const float4 fv = *(const float4*)&f[gl * FEAT + 4 * ql];
            const float4 wf = *(const float4*)&ws[fbase + 4 * (ql & 3)];
            const float p = red16(dot4(fv, wf));
            if (ql == 15) ws[PSUM_OFF + a] = p;
        }
    } else {
        const int gb = bid - NB - EB - FB;  // 0..15
        const float4 g4 = *(const float4*)&ws[4 * s];
        for (int u = gb * 8 + hw; u < N_GRAPHS; u += GB * 8) {
            const float4 x = *(const float4*)&globs[u * HID + 4 * s];
            const float a = red32(dot4(x, g4));
            if (s == 31) ws[GSCAL_OFF + u] = a;
        }
    }
}

// One lane per action row (300K): 1-3 scalar table lookups, group-of-4 DPP
// sum, writing lane adds psum + constants and stores out[a].
__global__ __launch_bounds__(256) void final_kernel(
    const int* __restrict__ row, const int* __restrict__ col,
    const int* __restrict__ U, const int* __restrict__ V,
    const int* __restrict__ E,
    const float* __restrict__ ws, float* __restrict__ out)
{
    const int r = blockIdx.x * 256 + threadIdx.x;
    if (r >= 3 * N_PER) return;
    const int br = r / N_PER;            // 0=glob 1=node 2=edge
    const int g  = r - br * N_PER;

    float look, cb;
    if (br == 0) {
        look = ws[GSCAL_OFF + U[g]];
        cb = ws[688];
    } else if (br == 1) {
        look = ws[NSCAL_OFF + 4 * V[g] + 2];
        cb = ws[689];
    } else {
        const int e = E[g];
        look = ws[ESCAL_OFF + g]
             + ws[NSCAL_OFF + 4 * row[e] + 0]
             + ws[NSCAL_OFF + 4 * col[e] + 1];
        cb = ws[690];
    }
    // sum within groups of 4 lanes (valid in lane 3 mod 4)
    float s4 = look;
    s4 += dpp_mov<0x111>(s4);
    s4 += dpp_mov<0x112>(s4);
    if ((threadIdx.x & 3) == 3) {
        const int a = r >> 2;            // global action id (layout matches)
        out[a] = s4 + ws[PSUM_OFF + a] + 4.f * cb + ws[691];
    }
}

extern "C" void kernel_launch(void* const* d_in, const int* in_sizes, int n_in,
                              void* d_out, int out_size, void* d_ws, size_t ws_size,
                              hipStream_t stream)
{
    const float* globs  = (const float*)d_in[0];
    const float* nodes  = (const float*)d_in[1];
    const float* edges  = (const float*)d_in[2];
    const float* ag     = (const float*)d_in[3];
    const float* an     = (const float*)d_in[4];
    const float* ae     = (const float*)d_in[5];
    const float* glob_W = (const float*)d_in[6];
    const float* glob_b = (const float*)d_in[7];
    const float* node_W = (const float*)d_in[8];
    const float* node_b = (const float*)d_in[9];
    const float* e1_W   = (const float*)d_in[10];
    const float* e1_b   = (const float*)d_in[11];
    const float* e2_W   = (const float*)d_in[12];
    const float* e2_b   = (const float*)d_in[13];
    const float* pol_W  = (const float*)d_in[14];
    const float* pol_b  = (const float*)d_in[15];
    const int*   row    = (const int*)d_in[16];
    const int*   col    = (const int*)d_in[17];
    const int*   U      = (const int*)d_in[18];
    const int*   V      = (const int*)d_in[20];
    const int*   E      = (const int*)d_in[22];

    float* ws  = (float*)d_ws;
    float* out = (float*)d_out;

    hipLaunchKernelGGL(fold_kernel, dim3(44), dim3(1024), 0, stream,
                       glob_W, glob_b, node_W, node_b, e1_W, e1_b, e2_W, e2_b,
                       pol_W, pol_b, ws);
    hipLaunchKernelGGL(work_kernel, dim3(WORK_BLOCKS), dim3(256), 0, stream,
                       nodes, globs, edges, ag, an, ae, E, ws);
    hipLaunchKernelGGL(final_kernel, dim3((3 * N_PER + 255) / 256), dim3(256),
                       0, stream, row, col, U, V, E, ws, out);
}